// Round 6
// baseline (114.477 us; speedup 1.0000x reference)
//
#include <hip/hip_runtime.h>
#include <cstdint>

// DST-II via FFT: TWO real rows packed into ONE complex 1024-pt FFT per wave.
// Y_k = DCT-II(u)_{N-1-k}, u_n = (-1)^n x_n; Makhoul: v_p = x_{2p} (p<512),
// v_p = -x_{2047-2p} (p>=512); V = DFT_1024(v); C_j = Re[e^{-i pi j/2048} V_j];
// Y_k = C_{1023-k}.
//
// Packing: z = vA + i*vB (rows 2*wid, 2*wid+1). One complex DFT_1024 serves
// both rows. Hermitian separation is fused into the DCT post-twiddle VIA
// SHUFFLES (R6): for partner j' = 1024-j the rotation satisfies
// (cos',sin') = (sin,cos), so with half-scaled rotation (hpc,hps) and
//   A = re*hpc + im*hps,  B = re*hps - im*hpc   (computed per lane, per s2)
// the outputs are  YA[1023-j] = A + shfl(B, Lp),  YB[1023-j] = shfl(A, Lp) - B.
// No LDS staging, no drains, single forward rotation recurrence. Only j=0 is
// self-paired with a broken identity (theta=0 != pi/2-0) -> lane-0 patch:
// YA = 2A, YB = -2B. (j=512 self-pair satisfies the identity, theta=pi/4.)
//
// DFT_1024, n = l + 64*n2 (l = lane, n2 = slot):
//  in-lane DIF-16 over n2 -> slot s holds m2 = brev4(s); twiddle W1024^{l*m2}
//  via power ladder. DFT_64 over l (l = c + 4d): two-pass 4KB LDS transpose
//  (validated zero-conflict chunk-XOR layout), in-lane DIT-16 over d,
//  W64^{c*m} ladder, cross-lane DFT_4 (quad shuffles).
//  Final: lane (c,m2), register s2 holds V(j), j = m2 + 16*s2 + 256*e(c).
//
// Partner mapping (validated in R5): m2>0: lane' = (3-c)+4*(16-m2), reg 15-s2.
// m2=0: lane' = 3-c, reg (16-s2)&15; special (m2=0,s2=0): lane' = {0,1,3,2}[c].
// In the unrolled store loop both register variants are compile-time; the
// m2l==0 lanes select the second shuffle result.
//
// launch_bounds empirics: VGPR cap = 256/N; (256,8)->32 and (256,6)->40 both
// spilled 120-170MB/dispatch; (256,3)->84 spill-free on the unpacked kernel;
// (256,2)->128 is spill insurance here. R1/R2: spills cost far more than one
// wave of occupancy.

static constexpr int BR4[16] = {0, 8, 4, 12, 2, 10, 6, 14,
                                1, 9, 5, 13, 3, 11, 7, 15};
// W16^o = e^{-2 pi i o/16}
static constexpr float W16C[8] = {1.0f, 0.9238795325f, 0.7071067812f,
                                  0.3826834324f, 0.0f, -0.3826834324f,
                                  -0.7071067812f, -0.9238795325f};
static constexpr float W16S[8] = {-0.0f, -0.3826834324f, -0.7071067812f,
                                  -0.9238795325f, -1.0f, -0.9238795325f,
                                  -0.7071067812f, -0.3826834324f};

__device__ __forceinline__ float sinr(float r) {   // sin(2*pi*r)
  return __builtin_amdgcn_sinf(r);
}
__device__ __forceinline__ float cosr(float r) {   // cos(2*pi*r), r in [0,1)
  float t = r + 0.25f;
  t -= (t >= 1.0f) ? 1.0f : 0.0f;
  return __builtin_amdgcn_sinf(t);
}

// (yr,yi) = (xr,xi) * W16^tw; trivial cases folded by hand (no fast-math).
__device__ __forceinline__ void twmul(int tw, float xr, float xi,
                                      float& yr, float& yi) {
  if (tw == 0) {
    yr = xr; yi = xi;
  } else if (tw == 4) {
    yr = xi; yi = -xr;
  } else if (tw == 2) {
    yr = 0.70710678118f * (xr + xi);
    yi = 0.70710678118f * (xi - xr);
  } else if (tw == 6) {
    yr = 0.70710678118f * (xi - xr);
    yi = -0.70710678118f * (xr + xi);
  } else {
    yr = xr * W16C[tw] - xi * W16S[tw];
    yi = xr * W16S[tw] + xi * W16C[tw];
  }
}

__global__ __launch_bounds__(256, 2) void dst_fft(const float* __restrict__ X,
                                                  float* __restrict__ Y) {
  // per-wave transpose buffer: 64 rows x 4 float4 chunks = 4 KB
  __shared__ __align__(16) float lds_all[4][64 * 16];

  const int t = threadIdx.x;
  const int l = t & 63;
  const int w = t >> 6;
  float* lds = &lds_all[w][0];
  const int wid = blockIdx.x * 4 + w;           // 0..8191 packed row-pairs
  const int rowA = wid * 2;

  const int c = l & 3;
  const int m2l = l >> 2;                       // this lane's m2 after transpose
  const int e = ((c & 1) << 1) | (c >> 1);      // brev2(c)
  const int sstar = (int)(__brev((unsigned)m2l) >> 28);  // column with freq m2l
  const int pl = sstar >> 3;                    // which transpose pass feeds us
  const int ccs = (sstar >> 1) & 3;             // its chunk within that pass
  const int subo = (sstar & 1) * 2;             // float offset inside chunk

  // separation partner lanes
  const int Lp = (3 - c) + 4 * ((16 - m2l) & 15);   // standard partner lane
  const int Lp0 = (c < 2) ? c : (5 - c);            // partner for (m2=0,s2=0)

  // ---- load both rows ----
  const float* xa = X + (size_t)rowA * 1024;
  float2 la[8], lb[8];
#pragma unroll
  for (int j = 0; j < 8; ++j) la[j] = *(const float2*)(xa + 2 * l + 128 * j);
#pragma unroll
  for (int j = 0; j < 8; ++j)
    lb[j] = *(const float2*)(xa + 1024 + 2 * l + 128 * j);

  // ---- fold both rows (validated layout); z = vA + i*vB ----
  float re[16], im[16];
#pragma unroll
  for (int j = 0; j < 8; ++j) re[j] = la[j].x;
#pragma unroll
  for (int j = 0; j < 8; ++j) re[15 - j] = -__shfl_xor(la[j].y, 63);
#pragma unroll
  for (int j = 0; j < 8; ++j) im[j] = lb[j].x;
#pragma unroll
  for (int j = 0; j < 8; ++j) im[15 - j] = -__shfl_xor(lb[j].y, 63);

  // ---- in-lane DIF-16 over slots (generic complex, H=8..1) ----
#pragma unroll
  for (int H = 8; H >= 1; H >>= 1) {
#pragma unroll
    for (int b = 0; b < 16; b += 2 * H) {
#pragma unroll
      for (int o = 0; o < H; ++o) {
        int i0 = b + o, i1 = i0 + H;
        float ar = re[i0] - re[i1], ai = im[i0] - im[i1];
        re[i0] += re[i1];
        im[i0] += im[i1];
        twmul(o * (8 / H), ar, ai, re[i1], im[i1]);
      }
    }
  }

  // ---- twiddle W1024^{l*m2}: power ladder off base e^{-2pi i l/1024} ----
  {
    float rb = (float)l * (1.0f / 1024.0f);
    float wr = cosr(rb), wi = -sinr(rb);
    float cr = wr, ci = wi;
#pragma unroll
    for (int m2 = 1; m2 < 16; ++m2) {
      if (m2 > 1) {                       // advance ladder: c *= w
        float nr = cr * wr - ci * wi;
        ci = cr * wi + ci * wr;
        cr = nr;
      }
      int i = BR4[m2];
      float tr = re[i] * cr - im[i] * ci;
      im[i] = re[i] * ci + im[i] * cr;
      re[i] = tr;
    }
  }

  // ---- two-pass 4KB wave-level LDS transpose (no barrier; per-wave) ----
  float re2[16], im2[16];
#pragma unroll
  for (int p = 0; p < 2; ++p) {
    if (p)  // WAR: pass-0 reads must drain before overwriting
      __asm__ volatile("s_waitcnt lgkmcnt(0)" ::: "memory");
#pragma unroll
    for (int cc = 0; cc < 4; ++cc) {
      int ch = 4 * p + cc;
      float4 v = make_float4(re[2 * ch], im[2 * ch],
                             re[2 * ch + 1], im[2 * ch + 1]);
      *(float4*)(lds + l * 16 + ((cc ^ ((l >> 1) & 3)) & 3) * 4) = v;
    }
    __asm__ volatile("s_waitcnt lgkmcnt(0)" ::: "memory");  // RAW: writes done
    if (pl == p) {
#pragma unroll
      for (int i = 0; i < 16; ++i) {
        int r = c + 4 * BR4[i];               // bit-rev d -> DIT natural out
        int q = (ccs ^ ((r >> 1) & 3)) & 3;
        float2 v = *(const float2*)(lds + r * 16 + q * 4 + subo);
        re2[i] = v.x;
        im2[i] = v.y;
      }
    }
  }

  // ---- in-lane DIT-16 over d -> natural m ----
#pragma unroll
  for (int H = 1; H <= 8; H <<= 1) {
#pragma unroll
    for (int b = 0; b < 16; b += 2 * H) {
#pragma unroll
      for (int o = 0; o < H; ++o) {
        int i0 = b + o, i1 = i0 + H;
        float tr, ti;
        twmul(o * (8 / H), re2[i1], im2[i1], tr, ti);
        re2[i1] = re2[i0] - tr;
        im2[i1] = im2[i0] - ti;
        re2[i0] += tr;
        im2[i0] += ti;
      }
    }
  }

  // ---- twiddle W64^{c*m}: ladder off base e^{-2pi i c/64} ----
  {
    float rb = (float)c * (1.0f / 64.0f);
    float br = cosr(rb), bi = -sinr(rb);
    float cr = br, ci = bi;
#pragma unroll
    for (int m = 1; m < 16; ++m) {
      if (m > 1) {                        // advance ladder: c *= b
        float nr = cr * br - ci * bi;
        ci = cr * bi + ci * br;
        cr = nr;
      }
      float tr = re2[m] * cr - im2[m] * ci;
      im2[m] = re2[m] * ci + im2[m] * cr;
      re2[m] = tr;
    }
  }

  // ---- cross-lane DFT_4 over c: DIF radix-2 x2 (quad-perm shuffles) ----
  {
    const float sgA = (c & 2) ? -1.0f : 1.0f;
    const bool rot = (c == 3);               // *(-i) on high half
    const float sgB = (c & 1) ? -1.0f : 1.0f;
#pragma unroll
    for (int i = 0; i < 16; ++i) {
      float tr = __shfl_xor(re2[i], 2), ti = __shfl_xor(im2[i], 2);
      float ar = tr + sgA * re2[i], ai = ti + sgA * im2[i];
      float br = rot ? ai : ar;
      float bi = rot ? -ar : ai;
      tr = __shfl_xor(br, 1);
      ti = __shfl_xor(bi, 1);
      re2[i] = tr + sgB * br;
      im2[i] = ti + sgB * bi;
    }
  }

  // ---- A/B transform (half-scaled DCT rotation), in place ----
  //   A[s2] = re*hpc + im*hps   (-> re2[s2])
  //   B[s2] = re*hps - im*hpc   (-> im2[s2])
  const float DC = 0.99969881869620422f;   // cos(2*pi/256)
  const float DS = 0.02454122852291229f;   // sin(2*pi/256)
  {
    float r0 = (float)(m2l + 256 * e) * (1.0f / 4096.0f);   // < 0.1875
    float hpc = 0.5f * cosr(r0), hps = 0.5f * sinr(r0);
#pragma unroll
    for (int s2 = 0; s2 < 16; ++s2) {
      float A = re2[s2] * hpc + im2[s2] * hps;
      float B = re2[s2] * hps - im2[s2] * hpc;
      re2[s2] = A;
      im2[s2] = B;
      if (s2 < 15) {                      // rotate j -> j+16
        float nc = hpc * DC - hps * DS;
        hps = hps * DC + hpc * DS;
        hpc = nc;
      }
    }
  }

  // ---- shuffle-based separation + stores ----
  // YA[1023-j] = A + partnerB, YB[1023-j] = partnerA - B.
  float* ya = Y + (size_t)rowA * 1024 + (1023 - m2l - 256 * e);
  float* yb = ya + 1024;
#pragma unroll
  for (int s2 = 0; s2 < 16; ++s2) {
    const int r1 = (15 - s2) & 15;        // partner reg for m2>0 lanes
    const int r2 = (16 - s2) & 15;        // partner reg for m2=0 lanes
    const int lane2 = (s2 == 0) ? Lp0 : Lp;
    float QA1 = __shfl(re2[r1], Lp), QB1 = __shfl(im2[r1], Lp);
    float QA2 = __shfl(re2[r2], lane2), QB2 = __shfl(im2[r2], lane2);
    float QA = (m2l == 0) ? QA2 : QA1;
    float QB = (m2l == 0) ? QB2 : QB1;
    float oa = re2[s2] + QB;
    float ob = QA - im2[s2];
    if (s2 == 0) {                        // j=0 self-pair patch (lane 0 only)
      oa = (l == 0) ? re2[0] + re2[0] : oa;
      ob = (l == 0) ? -(im2[0] + im2[0]) : ob;
    }
    ya[-16 * s2] = oa;
    yb[-16 * s2] = ob;
  }
}

extern "C" void kernel_launch(void* const* d_in, const int* in_sizes, int n_in,
                              void* d_out, int out_size, void* d_ws, size_t ws_size,
                              hipStream_t stream) {
  const float* X = (const float*)d_in[0];
  float* Y = (float*)d_out;
  // 16384 rows / 2 rows per wave (packed) / 4 waves per block = 2048 blocks
  dst_fft<<<dim3(2048), dim3(256), 0, stream>>>(X, Y);
}